// Round 1
// baseline (57.222 us; speedup 1.0000x reference)
//
#include <hip/hip_runtime.h>

#define NPTS 8192
#define DIM  512
#define NK   64
#define DC   (DIM/4)   // 128 float4 chunks per row

// ---------------------------------------------------------------------------
// Prep: gather the 64 centroid rows, store transposed d-major as ct4[dc][k]
// (so the main kernel's lane-k read of ct4[dc*64+k] is a coalesced 1KB wave
// read), and compute per-centroid sum / sum-of-squares.
// ---------------------------------------------------------------------------
__global__ __launch_bounds__(64) void prep_kernel(
    const float* __restrict__ f, const int* __restrict__ cid,
    float4* __restrict__ ct4, float* __restrict__ sqc, float* __restrict__ sc)
{
    const int k = blockIdx.x;      // one block (one wave) per centroid
    const int lane = threadIdx.x;  // 64 lanes
    const float4* row = (const float4*)(f + (size_t)cid[k] * DIM);
    float4 a = row[lane * 2];
    float4 b = row[lane * 2 + 1];
    ct4[(lane * 2) * NK + k]     = a;
    ct4[(lane * 2 + 1) * NK + k] = b;
    float s = a.x + a.y + a.z + a.w + b.x + b.y + b.z + b.w;
    float q = a.x*a.x + a.y*a.y + a.z*a.z + a.w*a.w
            + b.x*b.x + b.y*b.y + b.z*b.z + b.w*b.w;
    #pragma unroll
    for (int off = 32; off; off >>= 1) {
        s += __shfl_xor(s, off);
        q += __shfl_xor(q, off);
    }
    if (lane == 0) { sqc[k] = q; sc[k] = s; }
}

// ---------------------------------------------------------------------------
// Main: each wave owns 8 consecutive points; lane <-> centroid k.
// Per dc step: 1 coalesced ct4 read (1KB/wave, L2-hot) + 8 wave-uniform
// float4 feature reads + 32 FMAs. Then packed-u64 butterfly min/argmin.
// ---------------------------------------------------------------------------
__global__ __launch_bounds__(256) void main_kernel(
    const float* __restrict__ f, const int* __restrict__ cid,
    const float4* __restrict__ ct4, const float* __restrict__ sqc,
    const float* __restrict__ sc, float* __restrict__ out)
{
    const int lane = threadIdx.x & 63;
    const int wave = __builtin_amdgcn_readfirstlane(threadIdx.x >> 6);
    const int gw   = blockIdx.x * 4 + wave;   // global wave id, 0..1023
    const int base = gw * 8;                  // first of this wave's 8 points

    const float mySq  = sqc[lane];
    const float myS   = sc[lane];
    const int   myCid = cid[lane];

    // Per-point row stats (sum, sum-of-squares), coalesced reads + butterfly.
    float srow[8], qrow[8];
    #pragma unroll
    for (int p = 0; p < 8; ++p) {
        const float4* rp = (const float4*)(f + (size_t)(base + p) * DIM);
        float4 a = rp[lane * 2];
        float4 b = rp[lane * 2 + 1];
        float s = a.x + a.y + a.z + a.w + b.x + b.y + b.z + b.w;
        float q = a.x*a.x + a.y*a.y + a.z*a.z + a.w*a.w
                + b.x*b.x + b.y*b.y + b.z*b.z + b.w*b.w;
        #pragma unroll
        for (int off = 32; off; off >>= 1) {
            s += __shfl_xor(s, off);
            q += __shfl_xor(q, off);
        }
        srow[p] = s; qrow[p] = q;
    }

    // Dot products: acc[p] = dot(f[base+p], centroid[lane])
    float acc[8] = {0.f,0.f,0.f,0.f,0.f,0.f,0.f,0.f};
    const float* fb = f + (size_t)base * DIM;
    for (int dc = 0; dc < DC; ++dc) {
        float4 c4 = ct4[dc * NK + lane];
        #pragma unroll
        for (int p = 0; p < 8; ++p) {
            const float4 fp = *(const float4*)(fb + p * DIM + dc * 4);
            acc[p] = fmaf(fp.x, c4.x, acc[p]);
            acc[p] = fmaf(fp.y, c4.y, acc[p]);
            acc[p] = fmaf(fp.z, c4.z, acc[p]);
            acc[p] = fmaf(fp.w, c4.w, acc[p]);
        }
    }

    // Epilogue: distance, min/argmin (first-index tie-break), centroid
    // override (last-write-wins = highest matching k), energy accumulation.
    float esum = 0.f;
    float yv   = 0.f;
    #pragma unroll
    for (int p = 0; p < 8; ++p) {
        const int i = base + p;
        float d2 = qrow[p] + mySq - 2.0f * acc[p]
                 + 2.0e-6f * (srow[p] - myS) + 5.12e-10f;
        float dist = sqrtf(fmaxf(d2, 0.0f));
        // dist >= 0 -> IEEE bits are order-preserving as uint.
        unsigned long long key =
            (((unsigned long long)__float_as_uint(dist)) << 6)
            | (unsigned long long)lane;
        #pragma unroll
        for (int off = 32; off; off >>= 1) {
            unsigned long long o = __shfl_xor(key, off);
            key = (o < key) ? o : key;
        }
        float dmin = __uint_as_float((unsigned)(key >> 6));
        float y    = (float)(unsigned)(key & 63ull);
        unsigned long long ball = __ballot(myCid == i);
        if (ball) y = (float)(63 - __clzll(ball));  // last write wins (max k)
        esum += dmin;
        if (lane == p) yv = y;
    }
    if (lane == 0) atomicAdd(out, -esum);
    if (lane < 8) out[1 + base + lane] = yv;
}

extern "C" void kernel_launch(void* const* d_in, const int* in_sizes, int n_in,
                              void* d_out, int out_size, void* d_ws, size_t ws_size,
                              hipStream_t stream) {
    const float* f   = (const float*)d_in[0];
    const int*   cid = (const int*)d_in[1];
    float*       out = (float*)d_out;

    float4* ct4 = (float4*)d_ws;                                   // 128 KB
    float*  sqc = (float*)((char*)d_ws + DC * NK * sizeof(float4)); // +64 f
    float*  sc  = sqc + NK;                                         // +64 f

    // Zero the energy accumulator every launch (graph-capture-safe).
    hipMemsetAsync(d_out, 0, sizeof(float), stream);

    prep_kernel<<<NK, 64, 0, stream>>>(f, cid, ct4, sqc, sc);
    main_kernel<<<NPTS / 32, 256, 0, stream>>>(f, cid, ct4, sqc, sc, out);
}